// Round 9
// baseline (5135.657 us; speedup 1.0000x reference)
//
#include <hip/hip_runtime.h>
#include <hip/hip_bf16.h>
#include <stdint.h>

typedef unsigned short u16;
typedef unsigned int u32;
typedef unsigned long long u64;
typedef __attribute__((ext_vector_type(8))) short bf16x8;
typedef __attribute__((ext_vector_type(4))) float f32x4;
typedef __attribute__((ext_vector_type(4))) u32 u32x4;

#define TT 512
#define WPS ((size_t)2048 * 1024)   // W^T plane stride (u16 elems), [n=2048][k=1024]
#define ZRS 8                       // Z ring slots
#define HRS 16                      // h1 ring slots
#define HRS2 4                      // h2 ring slots

// ---- memory primitives ----
// C = cross-XCD coherent (L3 point).  L = intra-XCD (L2 point; sc0 bypasses own L1).
// Plain single-inst 8B store lands in own XCD's L2 (atomic transaction; tags catch tears).
#define LD16C(dst, addr) asm volatile("global_load_dwordx4 %0, %1, off sc0 sc1" : "=v"(dst) : "v"(addr))
#define LD8C(dst, addr)  asm volatile("global_load_dwordx2 %0, %1, off sc0 sc1" : "=v"(dst) : "v"(addr))
#define LD4C(dst, addr)  asm volatile("global_load_dword %0, %1, off sc0 sc1"   : "=v"(dst) : "v"(addr))
#define LD16L(dst, addr) asm volatile("global_load_dwordx4 %0, %1, off sc0"     : "=v"(dst) : "v"(addr))
#define LD8L(dst, addr)  asm volatile("global_load_dwordx2 %0, %1, off sc0"     : "=v"(dst) : "v"(addr))
#define ST4C(addr, v)    asm volatile("global_store_dword %0, %1, off sc0 sc1"  :: "v"(addr), "v"(v) : "memory")
#define ST8C(addr, v)    asm volatile("global_store_dwordx2 %0, %1, off sc0 sc1":: "v"(addr), "v"(v) : "memory")
#define ST16C(addr, v)   asm volatile("global_store_dwordx4 %0, %1, off sc0 sc1":: "v"(addr), "v"(v) : "memory")
#define ST8L(addr, v)    asm volatile("global_store_dwordx2 %0, %1, off"        :: "v"(addr), "v"(v) : "memory")
#define VM0()            do { asm volatile("s_waitcnt vmcnt(0)" ::: "memory"); \
                              __builtin_amdgcn_sched_barrier(0); } while (0)

__device__ __forceinline__ u16 f2bf(float f) {
  u32 u = __builtin_bit_cast(u32, f);
  return (u16)((u + 0x7FFFu + ((u >> 16) & 1u)) >> 16);   // RTNE
}
__device__ __forceinline__ float bf2f(u16 h) {
  u32 u = ((u32)h) << 16;
  return __builtin_bit_cast(float, u);
}
__device__ __forceinline__ float sigm(float x) { return 1.0f / (1.0f + expf(-x)); }
__device__ __forceinline__ f32x4 mfma16(bf16x8 a, bf16x8 b, f32x4 c) {
  return __builtin_amdgcn_mfma_f32_16x16x32_bf16(a, b, c, 0, 0, 0);
}
__device__ __forceinline__ u32 cvtpk(float a, float b) {
  u32 r;
  asm volatile("v_cvt_pk_bf16_f32 %0, %1, %2" : "=v"(r) : "v"(a), "v"(b));
  return r;
}
__device__ __forceinline__ void mark_err(u32* err) {
  __hip_atomic_fetch_add(err, 1u, __ATOMIC_RELAXED, __HIP_MEMORY_SCOPE_AGENT);
}
__device__ __forceinline__ u64 pack3(float v, u32 tag) {
  u16 p0 = f2bf(v); float r1 = v - bf2f(p0);
  u16 p1 = f2bf(r1); u16 p2 = f2bf(r1 - bf2f(p1));
  return (u64)((u32)p0 | ((u32)p1 << 16)) | ((u64)((u32)p2 | (tag << 16)) << 32);
}
__device__ __forceinline__ float zval(u64 w) {
  return bf2f((u16)(w & 0xFFFFu)) + bf2f((u16)((w >> 16) & 0xFFFFu))
       + bf2f((u16)((w >> 32) & 0xFFFFu));
}

// backpressure only: wait slots[ln&31] >= tgt; lastv caches monotone values
__device__ __forceinline__ void wait_slots(const u32* slots, int ln, u32 tgt,
                                           u32* lastv, int* bail, u32* err) {
  if (*bail) return;
  if (__ballot(*lastv < tgt) == 0ull) return;
  const u32* ptr = slots + (ln & 31);
  int n = 0;
  for (;;) {
    u32 v;
    LD4C(v, ptr);
    VM0();
    if (v > *lastv) *lastv = v;
    if (__ballot(*lastv < tgt) == 0ull) return;
    __builtin_amdgcn_s_sleep(2);
    if (++n > 400000) { *bail = 1; if (ln == 0) mark_err(err); return; }
  }
}

// all-producer head poll at the L3 point (lane ln covers producer ln>>1)
__device__ __forceinline__ void head_poll(const u64* p, u32 texp, u32* err) {
  int n = 0;
  for (;;) {
    u64 hw;
    LD8C(hw, p);
    VM0();
    if (__ballot((u32)(hw >> 48) != texp) == 0ull) return;
    __builtin_amdgcn_s_sleep(1);
    if (++n > 600000) { if ((threadIdx.x & 63) == 0) mark_err(err); return; }
  }
}

// ---------- prep: exact 3-plane bf16 split of W, transposed to [plane][n=2048][k=1024] ----------
__global__ void prep_w(const float* __restrict__ W, u16* __restrict__ WT) {
  int i = blockIdx.x * 256 + threadIdx.x;
  if (i >= 2048 * 1024) return;
  int n = i >> 10, k = i & 1023;
  float v = W[(size_t)k * 2048 + n];
  u16 p0 = f2bf(v);  float r  = v - bf2f(p0);
  u16 p1 = f2bf(r);  float r2 = r - bf2f(p1);
  u16 p2 = f2bf(r2);
  size_t o = (size_t)n * 1024 + k;
  WT[o] = p0;
  WT[WPS + o] = p1;
  WT[2 * WPS + o] = p2;
}

// ---------- chain block: 16 batch rows x 64 gate-cols (16 h-cols), K=512 h-part ----------
// Self-exchange of h through the XCD-shared L2 (hL); L3 ring (hG) kept for workers
// and as a sticky fallback if the blockIdx%8 -> XCD placement assumption fails.
template <int LAYER>
__device__ void chain(char* smem, int p, int bid,
                      const float* __restrict__ bias,
                      const u16* __restrict__ WT,
                      const u64* Zring, u64* hL, u64* hG,
                      const u32* progOther, u32* progSelf,
                      u16* h2hi, u32* err) {
  u16* wl = (u16*)smem;                         // [2 planes][64 rows][1024B] swizzled 128KB
  float* zl = (float*)(smem + 131072);          // [32][66] f32
  const int tid = threadIdx.x;

  // stage W h-part (k 512..1023) planes 0,1; row rho = gate*16 + hcol
#pragma unroll 1
  for (int it = 0; it < 32; ++it) {
    int id = it * 256 + tid;
    int pl = id >> 12, rem = id & 4095, rho = rem >> 6, m = rem & 63;
    int n = ((rho >> 4) << 9) + (bid << 4) + (rho & 15);
    u32x4 v = *(const u32x4*)(WT + (size_t)pl * WPS + (size_t)n * 1024 + 512 + m * 8);
    int dst = pl * 65536 + rho * 1024 + ((m << 4) ^ ((rho & 7) << 4));
    *(u32x4*)((char*)wl + dst) = v;
  }

  const int ln = tid & 63, kq = tid >> 6;       // kq = K-quarter (128 each)
  const int fr = ln & 15, kg8 = (ln >> 4) << 3;
  const int row = tid >> 4, hc = tid & 15;      // epilogue: (batch row, h-col)
  float bsv[4];
#pragma unroll
  for (int g = 0; g < 4; ++g) bsv[g] = bias[(g << 9) + (bid << 4) + hc];
  const int ka = kq * 128 + kg8;
  const u16* w2base[4];
#pragma unroll
  for (int nt = 0; nt < 4; ++nt)
    w2base[nt] = WT + 2 * WPS + (size_t)((nt << 9) + (bid << 4) + fr) * 1024 + 512 + ka;
  const int hrm = (LAYER == 1) ? (HRS - 1) : (HRS2 - 1);
  const int pcol = ((ln >> 1) << 4) + ((ln & 1) << 9);  // poll offset: row ln&1, col (ln>>1)*16

  float creg = 0.0f;
  u32 lastbp = 0;
  int bail = 0;
  int useG = 0;                                  // sticky L3 fallback
  __syncthreads();

#pragma unroll 1
  for (int t = 0; t < TT; ++t) {
    // backpressure: h1 ring overwrite gated transitively via L2 progress (L1 only)
    if (LAYER == 1 && kq == 0 && t >= HRS - 1)
      wait_slots(progOther, ln, (u32)(t - (HRS - 1)), &lastbp, &bail, err);

    const size_t soff = (size_t)(t & hrm) * (16 * 512);
    const u64* hbL = hL + soff + (size_t)fr * 512 + ka;
    const u64* hbG = hG + soff + (size_t)fr * 512 + ka;
    const u64* zb = Zring + (size_t)(t & (ZRS - 1)) * (16 * 2048) + (size_t)row * 2048
                  + (bid << 4) + hc;
    const u32 texp = (u32)t, zexp = (u32)(t + 1);

    // 1) speculative Z loads (validated in epilogue; MFMA doesn't need them)
    u64 zw[4];
#pragma unroll
    for (int g = 0; g < 4; ++g) LD8C(zw[g], zb + ((size_t)g << 9));

    // 2) readiness poll covering ALL 32 producers
    if (!useG) {
      int n = 0;
      for (;;) {
        u64 hw;
        LD8L(hw, hL + soff + pcol);
        VM0();
        if (__ballot((u32)(hw >> 48) != texp) == 0ull) break;
        __builtin_amdgcn_s_sleep(1);
        if (++n > 4000) { useG = 1; break; }     // placement wrong -> L3 path (sticky)
      }
    }
    if (useG) head_poll(hG + soff + pcol, texp, err);

    // 3) batch load + validate
    u32x4 hv[4][4];
    int tries = 0;
    for (;;) {
      if (!useG) {
#pragma unroll
        for (int kt = 0; kt < 4; ++kt)
#pragma unroll
          for (int j = 0; j < 4; ++j) LD16L(hv[kt][j], hbL + kt * 32 + 2 * j);
      } else {
#pragma unroll
        for (int kt = 0; kt < 4; ++kt)
#pragma unroll
          for (int j = 0; j < 4; ++j) LD16C(hv[kt][j], hbG + kt * 32 + 2 * j);
      }
      VM0();
      u32 bad = 0;
#pragma unroll
      for (int kt = 0; kt < 4; ++kt)
#pragma unroll
        for (int j = 0; j < 4; ++j)
          bad |= ((hv[kt][j].y >> 16) ^ texp) | ((hv[kt][j].w >> 16) ^ texp);
      if (__ballot(bad != 0) == 0ull) break;
      ++tries;
      if (tries == 64 && !useG) useG = 1;
      if (tries > 500000) { if (ln == 0) mark_err(err); break; }
      __builtin_amdgcn_s_sleep(1);
    }

    // 4) MFMA: 4 n-tiles (gates) x 4 k-tiles x 6 products
    f32x4 acc[4] = {{0.f,0.f,0.f,0.f},{0.f,0.f,0.f,0.f},{0.f,0.f,0.f,0.f},{0.f,0.f,0.f,0.f}};
#pragma unroll
    for (int kt = 0; kt < 4; ++kt) {
      u32 r0[4], r1[4], r2[4];
#pragma unroll
      for (int j = 0; j < 4; ++j) {
        u32 lo0 = hv[kt][j].x, hi0 = hv[kt][j].y, lo1 = hv[kt][j].z, hi1 = hv[kt][j].w;
        r0[j] = (lo0 & 0xFFFFu) | (lo1 << 16);
        r1[j] = (lo0 >> 16) | (lo1 & 0xFFFF0000u);
        r2[j] = (hi0 & 0xFFFFu) | (hi1 << 16);
      }
      bf16x8 a0 = __builtin_bit_cast(bf16x8, *(u32x4*)r0);
      bf16x8 a1 = __builtin_bit_cast(bf16x8, *(u32x4*)r1);
      bf16x8 a2 = __builtin_bit_cast(bf16x8, *(u32x4*)r2);
#pragma unroll
      for (int nt = 0; nt < 4; ++nt) {
        int rho = (nt << 4) + fr;
        int kb = ((ka + kt * 32) << 1) ^ ((rho & 7) << 4);
        bf16x8 w0 = *(const bf16x8*)((char*)wl + rho * 1024 + kb);
        bf16x8 w1 = *(const bf16x8*)((char*)wl + 65536 + rho * 1024 + kb);
        bf16x8 w2 = *(const bf16x8*)(w2base[nt] + kt * 32);
        acc[nt] = mfma16(a0, w0, acc[nt]);
        acc[nt] = mfma16(a1, w0, acc[nt]);
        acc[nt] = mfma16(a2, w0, acc[nt]);
        acc[nt] = mfma16(a0, w1, acc[nt]);
        acc[nt] = mfma16(a1, w1, acc[nt]);
        acc[nt] = mfma16(a0, w2, acc[nt]);
      }
    }
    const int r4 = (ln >> 4) << 2;
    if (kq < 2) {
#pragma unroll
      for (int nt = 0; nt < 4; ++nt)
#pragma unroll
        for (int r = 0; r < 4; ++r)
          zl[(kq * 16 + r4 + r) * 66 + (nt << 4) + fr] = acc[nt][r];
    }
    __syncthreads();
    if (kq >= 2) {
#pragma unroll
      for (int nt = 0; nt < 4; ++nt)
#pragma unroll
        for (int r = 0; r < 4; ++r)
          zl[((kq - 2) * 16 + r4 + r) * 66 + (nt << 4) + fr] += acc[nt][r];
    }
    __syncthreads();

    // 5) epilogue: validate Z now (overlapped with compute above), then gates
    int ztries = 0;
    for (;;) {
      u32 zbad = 0;
#pragma unroll
      for (int g = 0; g < 4; ++g) zbad |= ((u32)(zw[g] >> 48) ^ zexp);
      if (__ballot(zbad != 0) == 0ull) break;
      __builtin_amdgcn_s_sleep(1);
#pragma unroll
      for (int g = 0; g < 4; ++g) LD8C(zw[g], zb + ((size_t)g << 9));
      VM0();
      if (++ztries > 500000) { if (ln == 0) mark_err(err); break; }
    }
    float z4[4];
#pragma unroll
    for (int g = 0; g < 4; ++g)
      z4[g] = zl[row * 66 + (g << 4) + hc] + zl[(16 + row) * 66 + (g << 4) + hc]
            + zval(zw[g]) + bsv[g];
    float sf = sigm(z4[0]);
    float si = sigm(z4[1]);
    float tg = tanhf(z4[2]);
    float sog = sigm(z4[3]);
    float hn = sog * tanhf(creg);               // tanh of OLD c (faithful to reference)
    creg = creg * sf + tg * si;
    u64 word = pack3(hn, (u32)(t + 1));
    size_t ho = (size_t)((t + 1) & hrm) * (16 * 512) + (size_t)row * 512 + (bid << 4) + hc;
    ST8L(hL + ho, word);                        // fast path: own-XCD L2
    ST8C(hG + ho, word);                        // workers + fallback
    if (LAYER == 2)
      h2hi[(size_t)(t + 1) * 16384 + (size_t)(p * 16 + row) * 512 + (bid << 4) + hc] =
          (u16)(word & 0xFFFFu);
    __syncthreads();
    if (tid == 0) ST4C(progSelf + bid, (u32)(t + 1));  // backpressure flag
  }
}

// ---------- satellite worker: strip s (32 cols), parity q; Z0 (6 ahead) + Zc ----------
__device__ void worker(char* smem, int w, const float* __restrict__ x,
                       const u16* __restrict__ W0T, const u16* __restrict__ W1T,
                       const u64* h1G, u64* Z0R, u64* ZcR,
                       const u32* prog1, const u32* prog2, u32* err) {
  const int s = w & 63, q = w >> 6;
  u16* wl1 = (u16*)smem;                        // W1x slab [2][32][1024B] 64KB
  u16* wl0 = (u16*)(smem + 65536);              // W0x slab 64KB
  float* zl = (float*)(smem + 131072);          // [32][34]
  const int tid = threadIdx.x;

#pragma unroll 1
  for (int it = 0; it < 32; ++it) {             // stage both slabs (k<512), planes 0,1
    int id = it * 256 + tid;
    int sl = id >> 12, rem = id & 4095, pl = rem >> 11, rem2 = rem & 2047;
    int rho = rem2 >> 6, m = rem2 & 63;
    const u16* WT = sl ? W0T : W1T;
    u32x4 v = *(const u32x4*)(WT + (size_t)pl * WPS + (size_t)(32 * s + rho) * 1024 + m * 8);
    int dst = sl * 65536 + pl * 32768 + rho * 1024 + ((m << 4) ^ ((rho & 7) << 4));
    *(u32x4*)((char*)wl1 + dst) = v;
  }

  const int ln = tid & 63, kq = tid >> 6;
  const int fr = ln & 15, kg8 = (ln >> 4) << 3;
  const int row = tid >> 4, c2 = (tid & 15) * 2;
  const int ka = kq * 128 + kg8;
  const int pcol = ((ln >> 1) << 4) + ((ln & 1) << 9);
  u32 last2[2] = {0, 0}, lastbp[2] = {0, 0};
  int bail = 0;
  __syncthreads();

#pragma unroll 1
  for (int k = 0;; ++k) {
    int t = 2 * k + q;
    if (t > 511) break;

    // ---- Z0 jobs: x @ W0x (k<3 double-issue builds the 6-step lead) ----
    int nz = (k < 3) ? 2 : 1;
#pragma unroll 1
    for (int e = 0; e < nz; ++e) {
      int tz = (e == 0 && k < 3) ? t : t + 6;
      if (tz > 511) continue;
#pragma unroll 1
      for (int p = 0; p < 2; ++p) {
        if (kq == 0 && tz >= ZRS)
          wait_slots(prog1 + p * 32, ln, (u32)(tz - ZRS + 1), &lastbp[p], &bail, err);
        const float* xb = x + (size_t)(p * 16 + fr) * TT * 512 + (size_t)tz * 512 + ka;
        f32x4 acc[2] = {{0.f,0.f,0.f,0.f},{0.f,0.f,0.f,0.f}};
#pragma unroll
        for (int kt = 0; kt < 4; ++kt) {
          f32x4 f0 = *(const f32x4*)(xb + kt * 32);
          f32x4 f1 = *(const f32x4*)(xb + kt * 32 + 4);
          u32 r0[4], r1[4], r2[4];
#pragma unroll
          for (int j = 0; j < 4; ++j) {
            float v0 = (j < 2) ? f0[j * 2] : f1[(j - 2) * 2];
            float v1 = (j < 2) ? f0[j * 2 + 1] : f1[(j - 2) * 2 + 1];
            u32 pk0 = cvtpk(v0, v1);
            float h0 = __builtin_bit_cast(float, pk0 << 16);
            float h1f = __builtin_bit_cast(float, pk0 & 0xFFFF0000u);
            float q0 = v0 - h0, q1 = v1 - h1f;
            u32 pk1 = cvtpk(q0, q1);
            float g0 = __builtin_bit_cast(float, pk1 << 16);
            float g1 = __builtin_bit_cast(float, pk1 & 0xFFFF0000u);
            u32 s0 = __builtin_bit_cast(u32, q0 - g0);
            u32 s1 = __builtin_bit_cast(u32, q1 - g1);
            r0[j] = pk0; r1[j] = pk1;
            r2[j] = (s0 >> 16) | (s1 & 0xFFFF0000u);
          }
          bf16x8 a0 = __builtin_bit_cast(bf16x8, *(u32x4*)r0);
          bf16x8 a1 = __builtin_bit_cast(bf16x8, *(u32x4*)r1);
          bf16x8 a2 = __builtin_bit_cast(bf16x8, *(u32x4*)r2);
#pragma unroll
          for (int nt = 0; nt < 2; ++nt) {
            int rho = (nt << 4) + fr;
            int kb = ((ka + kt * 32) << 1) ^ ((rho & 7) << 4);
            bf16x8 w0 = *(const bf16x8*)((char*)wl0 + rho * 1024 + kb);
            bf16x8 w1 = *(const bf16x8*)((char*)wl0 + 32768 + rho * 1024 + kb);
            bf16x8 w2 = *(const bf16x8*)(W0T + 2 * WPS + (size_t)(32 * s + rho) * 1024 + ka + kt * 32);
            acc[nt] = mfma16(a0, w0, acc[nt]);
            acc[nt] = mfma16(a1, w0, acc[nt]);
            acc[nt] = mfma16(a2, w0, acc[nt]);
            acc[nt] = mfma16(a0, w1, acc[nt]);
            acc[nt] = mfma16(a1, w1, acc[nt]);
            acc[nt] = mfma16(a0, w2, acc[nt]);
          }
        }
        const int r4 = (ln >> 4) << 2;
        if (kq < 2) {
#pragma unroll
          for (int nt = 0; nt < 2; ++nt)
#pragma unroll
            for (int r = 0; r < 4; ++r)
              zl[(kq * 16 + r4 + r) * 34 + (nt << 4) + fr] = acc[nt][r];
        }
        __syncthreads();
        if (kq >= 2) {
#pragma unroll
          for (int nt = 0; nt < 2; ++nt)
#pragma unroll
            for (int r = 0; r < 4; ++r)
              zl[((kq - 2) * 16 + r4 + r) * 34 + (nt << 4) + fr] += acc[nt][r];
        }
        __syncthreads();
        float v0 = zl[row * 34 + c2] + zl[(16 + row) * 34 + c2];
        float v1 = zl[row * 34 + c2 + 1] + zl[(16 + row) * 34 + c2 + 1];
        u64 w0 = pack3(v0, (u32)(tz + 1));
        u64 w1 = pack3(v1, (u32)(tz + 1));
        u32x4 st = { (u32)w0, (u32)(w0 >> 32), (u32)w1, (u32)(w1 >> 32) };
        u64* dst = Z0R + (size_t)p * ZRS * 16 * 2048 + (size_t)(tz & (ZRS - 1)) * (16 * 2048)
                 + (size_t)row * 2048 + 32 * s + c2;
        ST16C(dst, st);
        __syncthreads();
      }
    }

    // ---- Zc jobs: h1(t+1) @ W1x (readiness via h tags; flags only for ring space) ----
#pragma unroll 1
    for (int p = 0; p < 2; ++p) {
      if (kq == 0 && t >= ZRS)
        wait_slots(prog2 + p * 32, ln, (u32)(t - ZRS + 1), &last2[p], &bail, err);
      const size_t sb = (size_t)p * HRS * 16 * 512 + (size_t)((t + 1) & (HRS - 1)) * (16 * 512);
      const u64* hb = h1G + sb + (size_t)fr * 512 + ka;
      const u32 texp = (u32)(t + 1);
      head_poll(h1G + sb + pcol, texp, err);    // all-producer coverage
      u32x4 hv[4][4];
      int tries = 0;
      for (;;) {
#pragma unroll
        for (int kt = 0; kt < 4; ++kt)
#pragma unroll
          for (int j = 0; j < 4; ++j) LD16C(hv[kt][j], hb + kt * 32 + 2 * j);
        VM0();
        u32 bad = 0;
#pragma unroll
        for (int kt = 0; kt < 4; ++kt)
#pragma unroll
          for (int j = 0; j < 4; ++j)
            bad |= ((hv[kt][j].y >> 16) ^ texp) | ((hv[kt][j].w >> 16) ^ texp);
        if (__ballot(bad != 0) == 0ull) break;
        if (++tries > 500000) { if (ln == 0) mark_err(err); break; }
        __builtin_amdgcn_s_sleep(1);
      }
      f32x4 acc[2] = {{0.f,0.f,0.f,0.f},{0.f,0.f,0.f,0.f}};
#pragma unroll
      for (int kt = 0; kt < 4; ++kt) {
        u32 r0[4], r1[4], r2[4];
#pragma unroll
        for (int j = 0; j < 4; ++j) {
          u32 lo0 = hv[kt][j].x, hi0 = hv[kt][j].y, lo1 = hv[kt][j].z, hi1 = hv[kt][j].w;
          r0[j] = (lo0 & 0xFFFFu) | (lo1 << 16);
          r1[j] = (lo0 >> 16) | (lo1 & 0xFFFF0000u);
          r2[j] = (hi0 & 0xFFFFu) | (hi1 << 16);
        }
        bf16x8 a0 = __builtin_bit_cast(bf16x8, *(u32x4*)r0);
        bf16x8 a1 = __builtin_bit_cast(bf16x8, *(u32x4*)r1);
        bf16x8 a2 = __builtin_bit_cast(bf16x8, *(u32x4*)r2);
#pragma unroll
        for (int nt = 0; nt < 2; ++nt) {
          int rho = (nt << 4) + fr;
          int kb = ((ka + kt * 32) << 1) ^ ((rho & 7) << 4);
          bf16x8 w0 = *(const bf16x8*)((char*)wl1 + rho * 1024 + kb);
          bf16x8 w1 = *(const bf16x8*)((char*)wl1 + 32768 + rho * 1024 + kb);
          bf16x8 w2 = *(const bf16x8*)(W1T + 2 * WPS + (size_t)(32 * s + rho) * 1024 + ka + kt * 32);
          acc[nt] = mfma16(a0, w0, acc[nt]);
          acc[nt] = mfma16(a1, w0, acc[nt]);
          acc[nt] = mfma16(a2, w0, acc[nt]);
          acc[nt] = mfma16(a0, w1, acc[nt]);
          acc[nt] = mfma16(a1, w1, acc[nt]);
          acc[nt] = mfma16(a0, w2, acc[nt]);
        }
      }
      const int r4 = (ln >> 4) << 2;
      if (kq < 2) {
#pragma unroll
        for (int nt = 0; nt < 2; ++nt)
#pragma unroll
          for (int r = 0; r < 4; ++r)
            zl[(kq * 16 + r4 + r) * 34 + (nt << 4) + fr] = acc[nt][r];
      }
      __syncthreads();
      if (kq >= 2) {
#pragma unroll
        for (int nt = 0; nt < 2; ++nt)
#pragma unroll
          for (int r = 0; r < 4; ++r)
            zl[((kq - 2) * 16 + r4 + r) * 34 + (nt << 4) + fr] += acc[nt][r];
      }
      __syncthreads();
      float v0 = zl[row * 34 + c2] + zl[(16 + row) * 34 + c2];
      float v1 = zl[row * 34 + c2 + 1] + zl[(16 + row) * 34 + c2 + 1];
      u64 w0 = pack3(v0, (u32)(t + 1));
      u64 w1 = pack3(v1, (u32)(t + 1));
      u32x4 st = { (u32)w0, (u32)(w0 >> 32), (u32)w1, (u32)(w1 >> 32) };
      u64* dst = ZcR + (size_t)p * ZRS * 16 * 2048 + (size_t)(t & (ZRS - 1)) * (16 * 2048)
               + (size_t)row * 2048 + 32 * s + c2;
      ST16C(dst, st);
      __syncthreads();
    }
  }
}

// ---------- persistent kernel: 256 blocks; r8 = role -> chains of one layer-pipe share an XCD ----------
__global__ void __launch_bounds__(256, 1) mega(
    const float* __restrict__ x,
    const float* __restrict__ bias0, const float* __restrict__ bias1,
    const u16* __restrict__ W0T, const u16* __restrict__ W1T,
    u64* Z0R, u64* ZcR, u64* h1L, u64* h1G, u64* h2L, u64* h2G,
    u16* h2hi, u32* flags) {
  __shared__ char smem[139520];
  const int blk = blockIdx.x;
  const int r8 = blk & 7, g8 = blk >> 3;
  u32* prog1 = flags;          // [2][32]
  u32* prog2 = flags + 64;     // [2][32]
  u32* err = flags + 128;
  if (r8 < 2) {
    int p = r8;
    chain<1>(smem, p, g8, bias0, W0T,
             Z0R + (size_t)p * ZRS * 16 * 2048,
             h1L + (size_t)p * HRS * 16 * 512, h1G + (size_t)p * HRS * 16 * 512,
             prog2 + p * 32, prog1 + p * 32, nullptr, err);
  } else if (r8 < 4) {
    int p = r8 - 2;
    chain<2>(smem, p, g8, bias1, W1T,
             ZcR + (size_t)p * ZRS * 16 * 2048,
             h2L + (size_t)p * HRS2 * 16 * 512, h2G + (size_t)p * HRS2 * 16 * 512,
             nullptr, prog2 + p * 32, h2hi, err);
  } else {
    worker(smem, (r8 - 4) * 32 + g8, x, W0T, W1T, h1G, Z0R, ZcR, prog1, prog2, err);
  }
}

// ---------- projection from bf16-hi h2 history ----------
__global__ void proj(const u16* __restrict__ y,
                     const float* __restrict__ Wr, const float* __restrict__ br,
                     float* __restrict__ out) {
  int gw = (blockIdx.x * blockDim.x + threadIdx.x) >> 6;
  int ln = threadIdx.x & 63;
  int t = gw >> 5, b = gw & 31;
  const u16* yp = y + (size_t)(t + 1) * 16384 + (size_t)b * 512 + ln * 8;
  u32x4 v = *(const u32x4*)yp;
  float p0 = 0.f, p1 = 0.f;
#pragma unroll
  for (int jj = 0; jj < 8; ++jj) {
    u16 hh = (u16)((v[jj >> 1] >> ((jj & 1) * 16)) & 0xFFFFu);
    float yv = bf2f(hh);
    int j = ln * 8 + jj;
    p0 += yv * Wr[j * 2 + 0];
    p1 += yv * Wr[j * 2 + 1];
  }
#pragma unroll
  for (int o = 32; o; o >>= 1) { p0 += __shfl_down(p0, o, 64); p1 += __shfl_down(p1, o, 64); }
  if (ln == 0) {
    out[((size_t)b * 512 + t) * 2 + 0] = p0 + br[0];
    out[((size_t)b * 512 + t) * 2 + 1] = p1 + br[1];
  }
}

// ---------- diagnostics ----------
__global__ void fail_mark(float* out, float code) {
  if (threadIdx.x == 0 && blockIdx.x == 0) out[0] = code;
}
__global__ void err_check(const u32* flags, float* out) {
  if (threadIdx.x == 0 && blockIdx.x == 0) {
    u32 e = flags[128];
    if (e) out[0] = 1.0e6f + (float)e;
  }
}

// ---------- host ----------
extern "C" void kernel_launch(void* const* d_in, const int* in_sizes, int n_in,
                              void* d_out, int out_size, void* d_ws, size_t ws_size,
                              hipStream_t stream) {
  (void)in_sizes; (void)n_in; (void)out_size;
  const float* x  = (const float*)d_in[0];
  const float* W0 = (const float*)d_in[1];
  const float* b0 = (const float*)d_in[2];
  const float* W1 = (const float*)d_in[3];
  const float* b1 = (const float*)d_in[4];
  const float* Wr = (const float*)d_in[5];
  const float* br = (const float*)d_in[6];
  float* out = (float*)d_out;

  char* ws = (char*)d_ws;
  size_t off = 0;
  auto take = [&](size_t n) { char* p = ws + off; off = (off + n + 255) & ~(size_t)255; return p; };

  u16* W0T  = (u16*)take(3 * WPS * 2);                          // 12.6 MB
  u16* W1T  = (u16*)take(3 * WPS * 2);                          // 12.6 MB
  u64* Z0R  = (u64*)take((size_t)2 * ZRS * 16 * 2048 * 8);      // 4.2 MB
  u64* ZcR  = (u64*)take((size_t)2 * ZRS * 16 * 2048 * 8);      // 4.2 MB
  u64* h1L  = (u64*)take((size_t)2 * HRS * 16 * 512 * 8);       // 2.1 MB
  u64* h1G  = (u64*)take((size_t)2 * HRS * 16 * 512 * 8);       // 2.1 MB
  u64* h2L  = (u64*)take((size_t)2 * HRS2 * 16 * 512 * 8);      // 0.52 MB
  u64* h2G  = (u64*)take((size_t)2 * HRS2 * 16 * 512 * 8);      // 0.52 MB
  u16* h2hi = (u16*)take((size_t)513 * 16384 * 2);              // 16.8 MB
  u32* flags = (u32*)take(129 * 4);                             // total ~56 MB

  if (off > ws_size) {                   // visible failure: absmax ~= 2e6
    fail_mark<<<1, 1, 0, stream>>>(out, 2.0e6f);
    return;
  }

  (void)hipMemsetAsync(flags, 0, 129 * 4, stream);
  // zero ALL rings (h(0)=0 with tag 0; no garbage can alias a future tag); replay-safe
  (void)hipMemsetAsync(Z0R, 0, (size_t)2 * ZRS * 16 * 2048 * 8, stream);
  (void)hipMemsetAsync(ZcR, 0, (size_t)2 * ZRS * 16 * 2048 * 8, stream);
  (void)hipMemsetAsync(h1L, 0, (size_t)2 * HRS * 16 * 512 * 8, stream);
  (void)hipMemsetAsync(h1G, 0, (size_t)2 * HRS * 16 * 512 * 8, stream);
  (void)hipMemsetAsync(h2L, 0, (size_t)2 * HRS2 * 16 * 512 * 8, stream);
  (void)hipMemsetAsync(h2G, 0, (size_t)2 * HRS2 * 16 * 512 * 8, stream);

  prep_w<<<8192, 256, 0, stream>>>(W0, W0T);
  prep_w<<<8192, 256, 0, stream>>>(W1, W1T);
  (void)hipGetLastError();
  mega<<<256, 256, 0, stream>>>(x, b0, b1, W0T, W1T,
                                Z0R, ZcR, h1L, h1G, h2L, h2G, h2hi, flags);
  if (hipGetLastError() != hipSuccess) {  // visible failure: absmax ~= 3e6
    fail_mark<<<1, 1, 0, stream>>>(out, 3.0e6f);
    return;
  }
  proj<<<4096, 256, 0, stream>>>(h2hi, Wr, br, out);
  err_check<<<1, 1, 0, stream>>>(flags, out);   // absmax ~= 1e6+n on timeout
}

// Round 12
// 4055.856 us; speedup vs baseline: 1.2662x; 1.2662x over previous
//
#include <hip/hip_runtime.h>
#include <hip/hip_bf16.h>
#include <stdint.h>

typedef unsigned short u16;
typedef unsigned int u32;
typedef unsigned long long u64;
typedef __attribute__((ext_vector_type(8))) short bf16x8;
typedef __attribute__((ext_vector_type(4))) float f32x4;
typedef __attribute__((ext_vector_type(4))) u32 u32x4;

#define TT 512
#define WPS ((size_t)2048 * 1024)   // W^T plane stride (u16), [n=2048][k=1024]
#define ZRS 8                       // Z ring slots
#define HRS 16                      // h1 ring slots
#define HRS2 4                      // h2 ring slots

// ---- L3-point access primitives; ALL tagged words use single-instruction forms ----
#define LD16C(dst, addr) asm volatile("global_load_dwordx4 %0, %1, off sc0 sc1" : "=v"(dst) : "v"(addr))
#define LD8C(dst, addr)  asm volatile("global_load_dwordx2 %0, %1, off sc0 sc1" : "=v"(dst) : "v"(addr))
#define LD4C(dst, addr)  asm volatile("global_load_dword %0, %1, off sc0 sc1"   : "=v"(dst) : "v"(addr))
#define ST4C(addr, v)    asm volatile("global_store_dword %0, %1, off sc0 sc1"  :: "v"(addr), "v"(v) : "memory")
#define ST8C(addr, v)    asm volatile("global_store_dwordx2 %0, %1, off sc0 sc1":: "v"(addr), "v"(v) : "memory")
#define ST16C(addr, v)   asm volatile("global_store_dwordx4 %0, %1, off sc0 sc1":: "v"(addr), "v"(v) : "memory")
#define VM0()            do { asm volatile("s_waitcnt vmcnt(0)" ::: "memory"); \
                              __builtin_amdgcn_sched_barrier(0); } while (0)

__device__ __forceinline__ u16 f2bf(float f) {
  u32 u = __builtin_bit_cast(u32, f);
  return (u16)((u + 0x7FFFu + ((u >> 16) & 1u)) >> 16);   // RTNE
}
__device__ __forceinline__ float bf2f(u16 h) {
  u32 u = ((u32)h) << 16;
  return __builtin_bit_cast(float, u);
}
__device__ __forceinline__ float sigm(float x) { return 1.0f / (1.0f + expf(-x)); }
__device__ __forceinline__ f32x4 mfma16(bf16x8 a, bf16x8 b, f32x4 c) {
  return __builtin_amdgcn_mfma_f32_16x16x32_bf16(a, b, c, 0, 0, 0);
}
__device__ __forceinline__ u32 cvtpk(float a, float b) {
  u32 r;
  asm volatile("v_cvt_pk_bf16_f32 %0, %1, %2" : "=v"(r) : "v"(a), "v"(b));
  return r;
}
__device__ __forceinline__ void mark_err(u32* err) {
  __hip_atomic_fetch_add(err, 1u, __ATOMIC_RELAXED, __HIP_MEMORY_SCOPE_AGENT);
}
__device__ __forceinline__ u64 pack3(float v, u32 tag) {
  u16 p0 = f2bf(v); float r1 = v - bf2f(p0);
  u16 p1 = f2bf(r1); u16 p2 = f2bf(r1 - bf2f(p1));
  return (u64)((u32)p0 | ((u32)p1 << 16)) | ((u64)((u32)p2 | (tag << 16)) << 32);
}
__device__ __forceinline__ float zval(u64 w) {
  return bf2f((u16)(w & 0xFFFFu)) + bf2f((u16)((w >> 16) & 0xFFFFu))
       + bf2f((u16)((w >> 32) & 0xFFFFu));
}

// backpressure: wait slots[ln&31] >= tgt; lastv caches monotone values
__device__ __forceinline__ void wait_slots(const u32* slots, int ln, u32 tgt,
                                           u32* lastv, int* bail, u32* err) {
  if (*bail) return;
  if (__ballot(*lastv < tgt) == 0ull) return;
  const u32* ptr = slots + (ln & 31);
  int n = 0;
  for (;;) {
    u32 v;
    LD4C(v, ptr);
    VM0();
    if (v > *lastv) *lastv = v;
    if (__ballot(*lastv < tgt) == 0ull) return;
    __builtin_amdgcn_s_sleep(2);
    if (++n > 400000) { *bail = 1; if (ln == 0) mark_err(err); return; }
  }
}

// all-producer head poll (lane ln covers producer ln>>1 at rows {0,1})
__device__ __forceinline__ void head_poll(const u64* ptr, u32 texp, u32* err) {
  int n = 0;
  for (;;) {
    u64 hw;
    LD8C(hw, ptr);
    VM0();
    if (__ballot((u32)(hw >> 48) != texp) == 0ull) return;
    __builtin_amdgcn_s_sleep(1);
    if (++n > 600000) { if ((threadIdx.x & 63) == 0) mark_err(err); return; }
  }
}

// ---------- prep: exact 3-plane bf16 split of W, transposed to [plane][n=2048][k=1024] ----------
__global__ void prep_w(const float* __restrict__ W, u16* __restrict__ WT) {
  int i = blockIdx.x * 256 + threadIdx.x;
  if (i >= 2048 * 1024) return;
  int n = i >> 10, k = i & 1023;
  float v = W[(size_t)k * 2048 + n];
  u16 p0 = f2bf(v);  float r  = v - bf2f(p0);
  u16 p1 = f2bf(r);  float r2 = r - bf2f(p1);
  u16 p2 = f2bf(r2);
  size_t o = (size_t)n * 1024 + k;
  WT[o] = p0;
  WT[WPS + o] = p1;
  WT[2 * WPS + o] = p2;
}

// ---------- chain block (R7-proven structure): 16 rows x 64 gate-cols, K=512 self-h ----------
template <int LAYER>
__device__ void chain(char* smem, int p, int bid,
                      const float* __restrict__ bias,
                      const u16* __restrict__ WT,
                      const u64* Zring, u64* hG,
                      const u32* progOther, u32* progSelf,
                      u16* h2hi, u32* err) {
  u16* wl = (u16*)smem;                         // [2 planes][64 rows][1024B] swizzled 128KB
  float* zl = (float*)(smem + 131072);          // [32][66] f32
  const int tid = threadIdx.x;

#pragma unroll 1
  for (int it = 0; it < 32; ++it) {             // stage W h-part (k 512..1023) planes 0,1
    int id = it * 256 + tid;
    int pl = id >> 12, rem = id & 4095, rho = rem >> 6, m = rem & 63;
    int n = ((rho >> 4) << 9) + (bid << 4) + (rho & 15);
    u32x4 v = *(const u32x4*)(WT + (size_t)pl * WPS + (size_t)n * 1024 + 512 + m * 8);
    int dst = pl * 65536 + rho * 1024 + ((m << 4) ^ ((rho & 7) << 4));
    *(u32x4*)((char*)wl + dst) = v;
  }

  const int ln = tid & 63, kq = tid >> 6;       // kq = K-quarter (128 each of K=512)
  const int fr = ln & 15, kg8 = (ln >> 4) << 3;
  const int row = tid >> 4, hc = tid & 15;
  float bsv[4];
#pragma unroll
  for (int g = 0; g < 4; ++g) bsv[g] = bias[(g << 9) + (bid << 4) + hc];
  const int ka = kq * 128 + kg8;
  const u16* w2base[4];
#pragma unroll
  for (int nt = 0; nt < 4; ++nt)
    w2base[nt] = WT + 2 * WPS + (size_t)((nt << 9) + (bid << 4) + fr) * 1024 + 512 + ka;
  const int hrm = (LAYER == 1) ? (HRS - 1) : (HRS2 - 1);
  const int pcol = ((ln >> 1) << 4) + ((ln & 1) << 9);  // poll: row ln&1, col (ln>>1)*16

  float creg = 0.0f;
  u32 lastbp = 0;
  int bail = 0;
  __syncthreads();

#pragma unroll 1
  for (int t = 0; t < TT; ++t) {
    // h1 ring overwrite backpressure (L1 only): L2 must have consumed h1(t-15)
    if (LAYER == 1 && kq == 0 && t >= HRS - 1)
      wait_slots(progOther, ln, (u32)(t - (HRS - 1)), &lastbp, &bail, err);

    const size_t soff = (size_t)(t & hrm) * 8192;
    const u64* hb = hG + soff + (size_t)fr * 512 + ka;
    const u64* zb = Zring + (size_t)(t & (ZRS - 1)) * (16 * 2048) + (size_t)row * 2048
                  + (bid << 4) + hc;
    const u32 texp = (u32)t, zexp = (u32)(t + 1);

    // 1) speculative Z loads (validated in epilogue; MFMA doesn't need them)
    u64 zw[4];
#pragma unroll
    for (int g = 0; g < 4; ++g) LD8C(zw[g], zb + ((size_t)g << 9));

    // 2) readiness poll covering ALL 32 producers
    head_poll(hG + soff + pcol, texp, err);

    // 3) batch load + validate
    u32x4 hv[4][4];
    int tries = 0;
    for (;;) {
#pragma unroll
      for (int kt = 0; kt < 4; ++kt)
#pragma unroll
        for (int j = 0; j < 4; ++j) LD16C(hv[kt][j], hb + kt * 32 + 2 * j);
      VM0();
      u32 bad = 0;
#pragma unroll
      for (int kt = 0; kt < 4; ++kt)
#pragma unroll
        for (int j = 0; j < 4; ++j)
          bad |= ((hv[kt][j].y >> 16) ^ texp) | ((hv[kt][j].w >> 16) ^ texp);
      if (__ballot(bad != 0) == 0ull) break;
      if (++tries > 500000) { if (ln == 0) mark_err(err); break; }
      __builtin_amdgcn_s_sleep(1);
    }

    // 4) MFMA: 4 n-tiles (gates) x 4 k-tiles x 6 products
    f32x4 acc[4] = {{0.f,0.f,0.f,0.f},{0.f,0.f,0.f,0.f},{0.f,0.f,0.f,0.f},{0.f,0.f,0.f,0.f}};
#pragma unroll
    for (int kt = 0; kt < 4; ++kt) {
      u32 r0[4], r1[4], r2[4];
#pragma unroll
      for (int j = 0; j < 4; ++j) {
        u32 lo0 = hv[kt][j].x, hi0 = hv[kt][j].y, lo1 = hv[kt][j].z, hi1 = hv[kt][j].w;
        r0[j] = (lo0 & 0xFFFFu) | (lo1 << 16);
        r1[j] = (lo0 >> 16) | (lo1 & 0xFFFF0000u);
        r2[j] = (hi0 & 0xFFFFu) | (hi1 << 16);
      }
      bf16x8 a0 = __builtin_bit_cast(bf16x8, *(u32x4*)r0);
      bf16x8 a1 = __builtin_bit_cast(bf16x8, *(u32x4*)r1);
      bf16x8 a2 = __builtin_bit_cast(bf16x8, *(u32x4*)r2);
#pragma unroll
      for (int nt = 0; nt < 4; ++nt) {
        int rho = (nt << 4) + fr;
        int kb = ((ka + kt * 32) << 1) ^ ((rho & 7) << 4);
        bf16x8 w0 = *(const bf16x8*)((char*)wl + rho * 1024 + kb);
        bf16x8 w1 = *(const bf16x8*)((char*)wl + 65536 + rho * 1024 + kb);
        bf16x8 w2 = *(const bf16x8*)(w2base[nt] + kt * 32);
        acc[nt] = mfma16(a0, w0, acc[nt]);
        acc[nt] = mfma16(a1, w0, acc[nt]);
        acc[nt] = mfma16(a2, w0, acc[nt]);
        acc[nt] = mfma16(a0, w1, acc[nt]);
        acc[nt] = mfma16(a1, w1, acc[nt]);
        acc[nt] = mfma16(a0, w2, acc[nt]);
      }
    }
    const int r4 = (ln >> 4) << 2;
    if (kq < 2) {
#pragma unroll
      for (int nt = 0; nt < 4; ++nt)
#pragma unroll
        for (int r = 0; r < 4; ++r)
          zl[(kq * 16 + r4 + r) * 66 + (nt << 4) + fr] = acc[nt][r];
    }
    __syncthreads();
    if (kq >= 2) {
#pragma unroll
      for (int nt = 0; nt < 4; ++nt)
#pragma unroll
        for (int r = 0; r < 4; ++r)
          zl[((kq - 2) * 16 + r4 + r) * 66 + (nt << 4) + fr] += acc[nt][r];
    }
    __syncthreads();

    // 5) epilogue: validate Z now (overlapped with compute above), then gates
    int ztries = 0;
    for (;;) {
      u32 zbad = 0;
#pragma unroll
      for (int g = 0; g < 4; ++g) zbad |= ((u32)(zw[g] >> 48) ^ zexp);
      if (__ballot(zbad != 0) == 0ull) break;
      __builtin_amdgcn_s_sleep(1);
#pragma unroll
      for (int g = 0; g < 4; ++g) LD8C(zw[g], zb + ((size_t)g << 9));
      VM0();
      if (++ztries > 500000) { if (ln == 0) mark_err(err); break; }
    }
    float z4[4];
#pragma unroll
    for (int g = 0; g < 4; ++g)
      z4[g] = zl[row * 66 + (g << 4) + hc] + zl[(16 + row) * 66 + (g << 4) + hc]
            + zval(zw[g]) + bsv[g];
    float sf = sigm(z4[0]);
    float si = sigm(z4[1]);
    float tg = tanhf(z4[2]);
    float sog = sigm(z4[3]);
    float hn = sog * tanhf(creg);               // tanh of OLD c (faithful to reference)
    creg = creg * sf + tg * si;
    u64 word = pack3(hn, (u32)(t + 1));
    size_t ho = (size_t)((t + 1) & hrm) * 8192 + (size_t)row * 512 + (bid << 4) + hc;
    ST8C(hG + ho, word);
    if (LAYER == 2)
      h2hi[(size_t)(t + 1) * 16384 + (size_t)(p * 16 + row) * 512 + (bid << 4) + hc] =
          (u16)(word & 0xFFFFu);
    __syncthreads();
    if (tid == 0) ST4C(progSelf + bid, (u32)(t + 1));  // progress flag (backpressure)
  }
}

// ---------- satellite worker (R7-proven): strip s (32 cols), parity q; Z0 (6 ahead) + Zc ----------
__device__ void worker(char* smem, int w, const float* __restrict__ x,
                       const u16* __restrict__ W0T, const u16* __restrict__ W1T,
                       const u64* h1G, u64* Z0R, u64* ZcR,
                       const u32* prog1, const u32* prog2, u32* err) {
  const int s = w & 63, q = w >> 6;
  u16* wl1 = (u16*)smem;                        // W1x slab [2][32][1024B] 64KB
  u16* wl0 = (u16*)(smem + 65536);              // W0x slab 64KB
  float* zl = (float*)(smem + 131072);          // [32][34]
  const int tid = threadIdx.x;

#pragma unroll 1
  for (int it = 0; it < 32; ++it) {             // stage both slabs (k<512), planes 0,1
    int id = it * 256 + tid;
    int sl = id >> 12, rem = id & 4095, pl = rem >> 11, rem2 = rem & 2047;
    int rho = rem2 >> 6, m = rem2 & 63;
    const u16* WT = sl ? W0T : W1T;
    u32x4 v = *(const u32x4*)(WT + (size_t)pl * WPS + (size_t)(32 * s + rho) * 1024 + m * 8);
    int dst = sl * 65536 + pl * 32768 + rho * 1024 + ((m << 4) ^ ((rho & 7) << 4));
    *(u32x4*)((char*)wl1 + dst) = v;
  }

  const int ln = tid & 63, kq = tid >> 6;
  const int fr = ln & 15, kg8 = (ln >> 4) << 3;
  const int row = tid >> 4, c2 = (tid & 15) * 2;
  const int ka = kq * 128 + kg8;
  const int pcol = ((ln >> 1) << 4) + ((ln & 1) << 9);
  u32 last2[2] = {0, 0}, lastbp[2] = {0, 0};
  int bail = 0;
  __syncthreads();

#pragma unroll 1
  for (int k = 0;; ++k) {
    int t = 2 * k + q;
    if (t > 511) break;

    // ---- Z0 jobs: x @ W0x (k<3 double-issue builds the 6-step lead) ----
    int nz = (k < 3) ? 2 : 1;
#pragma unroll 1
    for (int e = 0; e < nz; ++e) {
      int tz = (e == 0 && k < 3) ? t : t + 6;
      if (tz > 511) continue;
#pragma unroll 1
      for (int p = 0; p < 2; ++p) {
        if (kq == 0 && tz >= ZRS)
          wait_slots(prog1 + p * 32, ln, (u32)(tz - ZRS + 1), &lastbp[p], &bail, err);
        const float* xb = x + (size_t)(p * 16 + fr) * TT * 512 + (size_t)tz * 512 + ka;
        f32x4 acc[2] = {{0.f,0.f,0.f,0.f},{0.f,0.f,0.f,0.f}};
#pragma unroll
        for (int kt = 0; kt < 4; ++kt) {
          f32x4 f0 = *(const f32x4*)(xb + kt * 32);
          f32x4 f1 = *(const f32x4*)(xb + kt * 32 + 4);
          u32 r0[4], r1[4], r2[4];
#pragma unroll
          for (int j = 0; j < 4; ++j) {
            float v0 = (j < 2) ? f0[j * 2] : f1[(j - 2) * 2];
            float v1 = (j < 2) ? f0[j * 2 + 1] : f1[(j - 2) * 2 + 1];
            u32 pk0 = cvtpk(v0, v1);
            float h0 = __builtin_bit_cast(float, pk0 << 16);
            float h1f = __builtin_bit_cast(float, pk0 & 0xFFFF0000u);
            float q0 = v0 - h0, q1 = v1 - h1f;
            u32 pk1 = cvtpk(q0, q1);
            float g0 = __builtin_bit_cast(float, pk1 << 16);
            float g1 = __builtin_bit_cast(float, pk1 & 0xFFFF0000u);
            u32 s0 = __builtin_bit_cast(u32, q0 - g0);
            u32 s1 = __builtin_bit_cast(u32, q1 - g1);
            r0[j] = pk0; r1[j] = pk1;
            r2[j] = (s0 >> 16) | (s1 & 0xFFFF0000u);
          }
          bf16x8 a0 = __builtin_bit_cast(bf16x8, *(u32x4*)r0);
          bf16x8 a1 = __builtin_bit_cast(bf16x8, *(u32x4*)r1);
          bf16x8 a2 = __builtin_bit_cast(bf16x8, *(u32x4*)r2);
#pragma unroll
          for (int nt = 0; nt < 2; ++nt) {
            int rho = (nt << 4) + fr;
            int kb = ((ka + kt * 32) << 1) ^ ((rho & 7) << 4);
            bf16x8 w0 = *(const bf16x8*)((char*)wl0 + rho * 1024 + kb);
            bf16x8 w1 = *(const bf16x8*)((char*)wl0 + 32768 + rho * 1024 + kb);
            bf16x8 w2 = *(const bf16x8*)(W0T + 2 * WPS + (size_t)(32 * s + rho) * 1024 + ka + kt * 32);
            acc[nt] = mfma16(a0, w0, acc[nt]);
            acc[nt] = mfma16(a1, w0, acc[nt]);
            acc[nt] = mfma16(a2, w0, acc[nt]);
            acc[nt] = mfma16(a0, w1, acc[nt]);
            acc[nt] = mfma16(a1, w1, acc[nt]);
            acc[nt] = mfma16(a0, w2, acc[nt]);
          }
        }
        const int r4 = (ln >> 4) << 2;
        if (kq < 2) {
#pragma unroll
          for (int nt = 0; nt < 2; ++nt)
#pragma unroll
            for (int r = 0; r < 4; ++r)
              zl[(kq * 16 + r4 + r) * 34 + (nt << 4) + fr] = acc[nt][r];
        }
        __syncthreads();
        if (kq >= 2) {
#pragma unroll
          for (int nt = 0; nt < 2; ++nt)
#pragma unroll
            for (int r = 0; r < 4; ++r)
              zl[((kq - 2) * 16 + r4 + r) * 34 + (nt << 4) + fr] += acc[nt][r];
        }
        __syncthreads();
        float v0 = zl[row * 34 + c2] + zl[(16 + row) * 34 + c2];
        float v1 = zl[row * 34 + c2 + 1] + zl[(16 + row) * 34 + c2 + 1];
        u64 w0 = pack3(v0, (u32)(tz + 1));
        u64 w1 = pack3(v1, (u32)(tz + 1));
        u32x4 st = { (u32)w0, (u32)(w0 >> 32), (u32)w1, (u32)(w1 >> 32) };
        u64* dst = Z0R + (size_t)p * ZRS * 16 * 2048 + (size_t)(tz & (ZRS - 1)) * (16 * 2048)
                 + (size_t)row * 2048 + 32 * s + c2;
        ST16C(dst, st);
        __syncthreads();
      }
    }

    // ---- Zc jobs: h1(t+1) @ W1x (readiness via h tags; flags only for ring space) ----
#pragma unroll 1
    for (int p = 0; p < 2; ++p) {
      if (kq == 0 && t >= ZRS)
        wait_slots(prog2 + p * 32, ln, (u32)(t - ZRS + 1), &last2[p], &bail, err);
      const size_t sb = (size_t)p * HRS * 8192 + (size_t)((t + 1) & (HRS - 1)) * 8192;
      const u64* hb = h1G + sb + (size_t)fr * 512 + ka;
      const u32 texp = (u32)(t + 1);
      head_poll(h1G + sb + pcol, texp, err);    // all-producer coverage
      u32x4 hv[4][4];
      int tries = 0;
      for (;;) {
#pragma unroll
        for (int kt = 0; kt < 4; ++kt)
#pragma unroll
          for (int j = 0; j < 4; ++j) LD16C(hv[kt][j], hb + kt * 32 + 2 * j);
        VM0();
        u32 bad = 0;
#pragma unroll
        for (int kt = 0; kt < 4; ++kt)
#pragma unroll
          for (int j = 0; j < 4; ++j)
            bad |= ((hv[kt][j].y >> 16) ^ texp) | ((hv[kt][j].w >> 16) ^ texp);
        if (__ballot(bad != 0) == 0ull) break;
        if (++tries > 500000) { if (ln == 0) mark_err(err); break; }
        __builtin_amdgcn_s_sleep(1);
      }
      f32x4 acc[2] = {{0.f,0.f,0.f,0.f},{0.f,0.f,0.f,0.f}};
#pragma unroll
      for (int kt = 0; kt < 4; ++kt) {
        u32 r0[4], r1[4], r2[4];
#pragma unroll
        for (int j = 0; j < 4; ++j) {
          u32 lo0 = hv[kt][j].x, hi0 = hv[kt][j].y, lo1 = hv[kt][j].z, hi1 = hv[kt][j].w;
          r0[j] = (lo0 & 0xFFFFu) | (lo1 << 16);
          r1[j] = (lo0 >> 16) | (lo1 & 0xFFFF0000u);
          r2[j] = (hi0 & 0xFFFFu) | (hi1 << 16);
        }
        bf16x8 a0 = __builtin_bit_cast(bf16x8, *(u32x4*)r0);
        bf16x8 a1 = __builtin_bit_cast(bf16x8, *(u32x4*)r1);
        bf16x8 a2 = __builtin_bit_cast(bf16x8, *(u32x4*)r2);
#pragma unroll
        for (int nt = 0; nt < 2; ++nt) {
          int rho = (nt << 4) + fr;
          int kb = ((ka + kt * 32) << 1) ^ ((rho & 7) << 4);
          bf16x8 w0 = *(const bf16x8*)((char*)wl1 + rho * 1024 + kb);
          bf16x8 w1 = *(const bf16x8*)((char*)wl1 + 32768 + rho * 1024 + kb);
          bf16x8 w2 = *(const bf16x8*)(W1T + 2 * WPS + (size_t)(32 * s + rho) * 1024 + ka + kt * 32);
          acc[nt] = mfma16(a0, w0, acc[nt]);
          acc[nt] = mfma16(a1, w0, acc[nt]);
          acc[nt] = mfma16(a2, w0, acc[nt]);
          acc[nt] = mfma16(a0, w1, acc[nt]);
          acc[nt] = mfma16(a1, w1, acc[nt]);
          acc[nt] = mfma16(a0, w2, acc[nt]);
        }
      }
      const int r4 = (ln >> 4) << 2;
      if (kq < 2) {
#pragma unroll
        for (int nt = 0; nt < 2; ++nt)
#pragma unroll
          for (int r = 0; r < 4; ++r)
            zl[(kq * 16 + r4 + r) * 34 + (nt << 4) + fr] = acc[nt][r];
      }
      __syncthreads();
      if (kq >= 2) {
#pragma unroll
        for (int nt = 0; nt < 2; ++nt)
#pragma unroll
          for (int r = 0; r < 4; ++r)
            zl[((kq - 2) * 16 + r4 + r) * 34 + (nt << 4) + fr] += acc[nt][r];
      }
      __syncthreads();
      float v0 = zl[row * 34 + c2] + zl[(16 + row) * 34 + c2];
      float v1 = zl[row * 34 + c2 + 1] + zl[(16 + row) * 34 + c2 + 1];
      u64 w0 = pack3(v0, (u32)(t + 1));
      u64 w1 = pack3(v1, (u32)(t + 1));
      u32x4 st = { (u32)w0, (u32)(w0 >> 32), (u32)w1, (u32)(w1 >> 32) };
      u64* dst = ZcR + (size_t)p * ZRS * 16 * 2048 + (size_t)(t & (ZRS - 1)) * (16 * 2048)
               + (size_t)row * 2048 + 32 * s + c2;
      ST16C(dst, st);
      __syncthreads();
    }
  }
}

// ---------- persistent kernel: 256 blocks, r8-role map (R7-proven dispatch) ----------
__global__ void __launch_bounds__(256, 1) mega(
    const float* __restrict__ x,
    const float* __restrict__ bias0, const float* __restrict__ bias1,
    const u16* __restrict__ W0T, const u16* __restrict__ W1T,
    u64* Z0R, u64* ZcR, u64* h1G, u64* h2G, u16* h2hi, u32* flags) {
  __shared__ char smem[139520];
  const int blk = blockIdx.x;
  const int r8 = blk & 7, g8 = blk >> 3;
  u32* prog1 = flags;          // [2][32]
  u32* prog2 = flags + 64;     // [2][32]
  u32* err = flags + 128;
  if (r8 < 2) {
    int p = r8;
    chain<1>(smem, p, g8, bias0, W0T,
             Z0R + (size_t)p * ZRS * 16 * 2048, h1G + (size_t)p * HRS * 8192,
             prog2 + p * 32, prog1 + p * 32, nullptr, err);
  } else if (r8 < 4) {
    int p = r8 - 2;
    chain<2>(smem, p, g8, bias1, W1T,
             ZcR + (size_t)p * ZRS * 16 * 2048, h2G + (size_t)p * HRS2 * 8192,
             nullptr, prog2 + p * 32, h2hi, err);
  } else {
    worker(smem, (r8 - 4) * 32 + g8, x, W0T, W1T, h1G, Z0R, ZcR, prog1, prog2, err);
  }
}

// ---------- projection from bf16-hi h2 history ----------
__global__ void proj(const u16* __restrict__ y,
                     const float* __restrict__ Wr, const float* __restrict__ br,
                     float* __restrict__ out) {
  int gw = (blockIdx.x * blockDim.x + threadIdx.x) >> 6;
  int ln = threadIdx.x & 63;
  int t = gw >> 5, b = gw & 31;
  const u16* yp = y + (size_t)(t + 1) * 16384 + (size_t)b * 512 + ln * 8;
  u32x4 v = *(const u32x4*)yp;
  float p0 = 0.f, p1 = 0.f;
#pragma unroll
  for (int jj = 0; jj < 8; ++jj) {
    u16 hh = (u16)((v[jj >> 1] >> ((jj & 1) * 16)) & 0xFFFFu);
    float yv = bf2f(hh);
    int j = ln * 8 + jj;
    p0 += yv * Wr[j * 2 + 0];
    p1 += yv * Wr[j * 2 + 1];
  }
#pragma unroll
  for (int o = 32; o; o >>= 1) { p0 += __shfl_down(p0, o, 64); p1 += __shfl_down(p1, o, 64); }
  if (ln == 0) {
    out[((size_t)b * 512 + t) * 2 + 0] = p0 + br[0];
    out[((size_t)b * 512 + t) * 2 + 1] = p1 + br[1];
  }
}

// ---------- diagnostics ----------
__global__ void fail_mark(float* out, float code) {
  if (threadIdx.x == 0 && blockIdx.x == 0) out[0] = code;
}
__global__ void err_check(const u32* flags, float* out) {
  if (threadIdx.x == 0 && blockIdx.x == 0) {
    u32 e = flags[128];
    if (e) out[0] = 1.0e6f + (float)e;
  }
}

// ---------- host ----------
extern "C" void kernel_launch(void* const* d_in, const int* in_sizes, int n_in,
                              void* d_out, int out_size, void* d_ws, size_t ws_size,
                              hipStream_t stream) {
  (void)in_sizes; (void)n_in; (void)out_size;
  const float* x  = (const float*)d_in[0];
  const float* W0 = (const float*)d_in[1];
  const float* b0 = (const float*)d_in[2];
  const float* W1 = (const float*)d_in[3];
  const float* b1 = (const float*)d_in[4];
  const float* Wr = (const float*)d_in[5];
  const float* br = (const float*)d_in[6];
  float* out = (float*)d_out;

  char* ws = (char*)d_ws;
  size_t off = 0;
  auto take = [&](size_t n) { char* p = ws + off; off = (off + n + 255) & ~(size_t)255; return p; };

  u16* W0T  = (u16*)take(3 * WPS * 2);                      // 12.6 MB
  u16* W1T  = (u16*)take(3 * WPS * 2);                      // 12.6 MB
  u64* Z0R  = (u64*)take((size_t)2 * ZRS * 16 * 2048 * 8);  // 4.2 MB
  u64* ZcR  = (u64*)take((size_t)2 * ZRS * 16 * 2048 * 8);  // 4.2 MB
  u64* h1G  = (u64*)take((size_t)2 * HRS * 8192 * 8);       // 2.1 MB
  u64* h2G  = (u64*)take((size_t)2 * HRS2 * 8192 * 8);      // 0.52 MB
  u16* h2hi = (u16*)take((size_t)513 * 16384 * 2);          // 16.8 MB
  u32* flags = (u32*)take(129 * 4);                         // total ~53 MB

  if (off > ws_size) {                   // visible failure: absmax ~= 2e6
    fail_mark<<<1, 1, 0, stream>>>(out, 2.0e6f);
    return;
  }

  (void)hipMemsetAsync(flags, 0, 129 * 4, stream);
  // zero ALL rings (h(0)=0 with tag 0; no garbage can alias a future tag); replay-safe
  (void)hipMemsetAsync(Z0R, 0, (size_t)2 * ZRS * 16 * 2048 * 8, stream);
  (void)hipMemsetAsync(ZcR, 0, (size_t)2 * ZRS * 16 * 2048 * 8, stream);
  (void)hipMemsetAsync(h1G, 0, (size_t)2 * HRS * 8192 * 8, stream);
  (void)hipMemsetAsync(h2G, 0, (size_t)2 * HRS2 * 8192 * 8, stream);

  prep_w<<<8192, 256, 0, stream>>>(W0, W0T);
  prep_w<<<8192, 256, 0, stream>>>(W1, W1T);
  (void)hipGetLastError();
  mega<<<256, 256, 0, stream>>>(x, b0, b1, W0T, W1T,
                                Z0R, ZcR, h1G, h2G, h2hi, flags);
  if (hipGetLastError() != hipSuccess) {  // visible failure: absmax ~= 3e6
    fail_mark<<<1, 1, 0, stream>>>(out, 3.0e6f);
    return;
  }
  proj<<<4096, 256, 0, stream>>>(h2hi, Wr, br, out);
  err_check<<<1, 1, 0, stream>>>(flags, out);   // absmax ~= 1e6+n on timeout
}

// Round 13
// 3535.735 us; speedup vs baseline: 1.4525x; 1.1471x over previous
//
#include <hip/hip_runtime.h>
#include <hip/hip_bf16.h>
#include <stdint.h>

typedef unsigned short u16;
typedef unsigned int u32;
typedef unsigned long long u64;
typedef __attribute__((ext_vector_type(8))) short bf16x8;
typedef __attribute__((ext_vector_type(4))) float f32x4;
typedef __attribute__((ext_vector_type(4))) u32 u32x4;

#define TT 512
#define WPS ((size_t)2048 * 1024)   // W^T plane stride (u16), [n=2048][k=1024]
#define ZRS 8                       // Z ring slots
#define HRS 16                      // h1 ring slots
#define HRS2 4                      // h2 ring slots

// ---- L3-point access primitives; ALL tagged words use single-instruction forms ----
#define LD16C(dst, addr) asm volatile("global_load_dwordx4 %0, %1, off sc0 sc1" : "=v"(dst) : "v"(addr))
#define LD8C(dst, addr)  asm volatile("global_load_dwordx2 %0, %1, off sc0 sc1" : "=v"(dst) : "v"(addr))
#define LD4C(dst, addr)  asm volatile("global_load_dword %0, %1, off sc0 sc1"   : "=v"(dst) : "v"(addr))
#define ST4C(addr, v)    asm volatile("global_store_dword %0, %1, off sc0 sc1"  :: "v"(addr), "v"(v) : "memory")
#define ST8C(addr, v)    asm volatile("global_store_dwordx2 %0, %1, off sc0 sc1":: "v"(addr), "v"(v) : "memory")
#define ST16C(addr, v)   asm volatile("global_store_dwordx4 %0, %1, off sc0 sc1":: "v"(addr), "v"(v) : "memory")
#define VM0()            do { asm volatile("s_waitcnt vmcnt(0)" ::: "memory"); \
                              __builtin_amdgcn_sched_barrier(0); } while (0)

__device__ __forceinline__ u16 f2bf(float f) {
  u32 u = __builtin_bit_cast(u32, f);
  return (u16)((u + 0x7FFFu + ((u >> 16) & 1u)) >> 16);   // RTNE
}
__device__ __forceinline__ float bf2f(u16 h) {
  u32 u = ((u32)h) << 16;
  return __builtin_bit_cast(float, u);
}
__device__ __forceinline__ float sigm(float x) { return 1.0f / (1.0f + expf(-x)); }
__device__ __forceinline__ f32x4 mfma16(bf16x8 a, bf16x8 b, f32x4 c) {
  return __builtin_amdgcn_mfma_f32_16x16x32_bf16(a, b, c, 0, 0, 0);
}
__device__ __forceinline__ u32 cvtpk(float a, float b) {
  u32 r;
  asm volatile("v_cvt_pk_bf16_f32 %0, %1, %2" : "=v"(r) : "v"(a), "v"(b));
  return r;
}
__device__ __forceinline__ void mark_err(u32* err) {
  __hip_atomic_fetch_add(err, 1u, __ATOMIC_RELAXED, __HIP_MEMORY_SCOPE_AGENT);
}
__device__ __forceinline__ u64 pack3(float v, u32 tag) {
  u16 p0 = f2bf(v); float r1 = v - bf2f(p0);
  u16 p1 = f2bf(r1); u16 p2 = f2bf(r1 - bf2f(p1));
  return (u64)((u32)p0 | ((u32)p1 << 16)) | ((u64)((u32)p2 | (tag << 16)) << 32);
}
__device__ __forceinline__ float zval(u64 w) {
  return bf2f((u16)(w & 0xFFFFu)) + bf2f((u16)((w >> 16) & 0xFFFFu))
       + bf2f((u16)((w >> 32) & 0xFFFFu));
}

// backpressure: wait slots[ln&31] >= tgt; lastv caches monotone values
__device__ __forceinline__ void wait_slots(const u32* slots, int ln, u32 tgt,
                                           u32* lastv, int* bail, u32* err) {
  if (*bail) return;
  if (__ballot(*lastv < tgt) == 0ull) return;
  const u32* ptr = slots + (ln & 31);
  int n = 0;
  for (;;) {
    u32 v;
    LD4C(v, ptr);
    VM0();
    if (v > *lastv) *lastv = v;
    if (__ballot(*lastv < tgt) == 0ull) return;
    __builtin_amdgcn_s_sleep(2);
    if (++n > 400000) { *bail = 1; if (ln == 0) mark_err(err); return; }
  }
}

// all-producer head poll (lane ln covers producer ln>>1 at rows {0,1})
__device__ __forceinline__ void head_poll(const u64* ptr, u32 texp, u32* err) {
  int n = 0;
  for (;;) {
    u64 hw;
    LD8C(hw, ptr);
    VM0();
    if (__ballot((u32)(hw >> 48) != texp) == 0ull) return;
    __builtin_amdgcn_s_sleep(1);
    if (++n > 600000) { if ((threadIdx.x & 63) == 0) mark_err(err); return; }
  }
}

// ---------- prep: exact 3-plane bf16 split of W, transposed to [plane][n=2048][k=1024] ----------
__global__ void prep_w(const float* __restrict__ W, u16* __restrict__ WT) {
  int i = blockIdx.x * 256 + threadIdx.x;
  if (i >= 2048 * 1024) return;
  int n = i >> 10, k = i & 1023;
  float v = W[(size_t)k * 2048 + n];
  u16 p0 = f2bf(v);  float r  = v - bf2f(p0);
  u16 p1 = f2bf(r);  float r2 = r - bf2f(p1);
  u16 p2 = f2bf(r2);
  size_t o = (size_t)n * 1024 + k;
  WT[o] = p0;
  WT[WPS + o] = p1;
  WT[2 * WPS + o] = p2;
}

// ---------- chain block (R12-proven, UNCHANGED): 16 rows x 64 gate-cols, K=512 self-h ----------
template <int LAYER>
__device__ void chain(char* smem, int p, int bid,
                      const float* __restrict__ bias,
                      const u16* __restrict__ WT,
                      const u64* Zring, u64* hG,
                      const u32* progOther, u32* progSelf,
                      u16* h2hi, u32* err) {
  u16* wl = (u16*)smem;                         // [2 planes][64 rows][1024B] swizzled 128KB
  float* zl = (float*)(smem + 131072);          // [32][66] f32
  const int tid = threadIdx.x;

#pragma unroll 1
  for (int it = 0; it < 32; ++it) {             // stage W h-part (k 512..1023) planes 0,1
    int id = it * 256 + tid;
    int pl = id >> 12, rem = id & 4095, rho = rem >> 6, m = rem & 63;
    int n = ((rho >> 4) << 9) + (bid << 4) + (rho & 15);
    u32x4 v = *(const u32x4*)(WT + (size_t)pl * WPS + (size_t)n * 1024 + 512 + m * 8);
    int dst = pl * 65536 + rho * 1024 + ((m << 4) ^ ((rho & 7) << 4));
    *(u32x4*)((char*)wl + dst) = v;
  }

  const int ln = tid & 63, kq = tid >> 6;       // kq = K-quarter (128 each of K=512)
  const int fr = ln & 15, kg8 = (ln >> 4) << 3;
  const int row = tid >> 4, hc = tid & 15;
  float bsv[4];
#pragma unroll
  for (int g = 0; g < 4; ++g) bsv[g] = bias[(g << 9) + (bid << 4) + hc];
  const int ka = kq * 128 + kg8;
  const u16* w2base[4];
#pragma unroll
  for (int nt = 0; nt < 4; ++nt)
    w2base[nt] = WT + 2 * WPS + (size_t)((nt << 9) + (bid << 4) + fr) * 1024 + 512 + ka;
  const int hrm = (LAYER == 1) ? (HRS - 1) : (HRS2 - 1);
  const int pcol = ((ln >> 1) << 4) + ((ln & 1) << 9);  // poll: row ln&1, col (ln>>1)*16

  float creg = 0.0f;
  u32 lastbp = 0;
  int bail = 0;
  __syncthreads();

#pragma unroll 1
  for (int t = 0; t < TT; ++t) {
    // h1 ring overwrite backpressure (L1 only): L2 must have consumed h1(t-15)
    if (LAYER == 1 && kq == 0 && t >= HRS - 1)
      wait_slots(progOther, ln, (u32)(t - (HRS - 1)), &lastbp, &bail, err);

    const size_t soff = (size_t)(t & hrm) * 8192;
    const u64* hb = hG + soff + (size_t)fr * 512 + ka;
    const u64* zb = Zring + (size_t)(t & (ZRS - 1)) * (16 * 2048) + (size_t)row * 2048
                  + (bid << 4) + hc;
    const u32 texp = (u32)t, zexp = (u32)(t + 1);

    // 1) speculative Z loads (validated in epilogue; MFMA doesn't need them)
    u64 zw[4];
#pragma unroll
    for (int g = 0; g < 4; ++g) LD8C(zw[g], zb + ((size_t)g << 9));

    // 2) readiness poll covering ALL 32 producers
    head_poll(hG + soff + pcol, texp, err);

    // 3) batch load + validate
    u32x4 hv[4][4];
    int tries = 0;
    for (;;) {
#pragma unroll
      for (int kt = 0; kt < 4; ++kt)
#pragma unroll
        for (int j = 0; j < 4; ++j) LD16C(hv[kt][j], hb + kt * 32 + 2 * j);
      VM0();
      u32 bad = 0;
#pragma unroll
      for (int kt = 0; kt < 4; ++kt)
#pragma unroll
        for (int j = 0; j < 4; ++j)
          bad |= ((hv[kt][j].y >> 16) ^ texp) | ((hv[kt][j].w >> 16) ^ texp);
      if (__ballot(bad != 0) == 0ull) break;
      if (++tries > 500000) { if (ln == 0) mark_err(err); break; }
      __builtin_amdgcn_s_sleep(1);
    }

    // 4) MFMA: 4 n-tiles (gates) x 4 k-tiles x 6 products
    f32x4 acc[4] = {{0.f,0.f,0.f,0.f},{0.f,0.f,0.f,0.f},{0.f,0.f,0.f,0.f},{0.f,0.f,0.f,0.f}};
#pragma unroll
    for (int kt = 0; kt < 4; ++kt) {
      u32 r0[4], r1[4], r2[4];
#pragma unroll
      for (int j = 0; j < 4; ++j) {
        u32 lo0 = hv[kt][j].x, hi0 = hv[kt][j].y, lo1 = hv[kt][j].z, hi1 = hv[kt][j].w;
        r0[j] = (lo0 & 0xFFFFu) | (lo1 << 16);
        r1[j] = (lo0 >> 16) | (lo1 & 0xFFFF0000u);
        r2[j] = (hi0 & 0xFFFFu) | (hi1 << 16);
      }
      bf16x8 a0 = __builtin_bit_cast(bf16x8, *(u32x4*)r0);
      bf16x8 a1 = __builtin_bit_cast(bf16x8, *(u32x4*)r1);
      bf16x8 a2 = __builtin_bit_cast(bf16x8, *(u32x4*)r2);
#pragma unroll
      for (int nt = 0; nt < 4; ++nt) {
        int rho = (nt << 4) + fr;
        int kb = ((ka + kt * 32) << 1) ^ ((rho & 7) << 4);
        bf16x8 w0 = *(const bf16x8*)((char*)wl + rho * 1024 + kb);
        bf16x8 w1 = *(const bf16x8*)((char*)wl + 65536 + rho * 1024 + kb);
        bf16x8 w2 = *(const bf16x8*)(w2base[nt] + kt * 32);
        acc[nt] = mfma16(a0, w0, acc[nt]);
        acc[nt] = mfma16(a1, w0, acc[nt]);
        acc[nt] = mfma16(a2, w0, acc[nt]);
        acc[nt] = mfma16(a0, w1, acc[nt]);
        acc[nt] = mfma16(a1, w1, acc[nt]);
        acc[nt] = mfma16(a0, w2, acc[nt]);
      }
    }
    const int r4 = (ln >> 4) << 2;
    if (kq < 2) {
#pragma unroll
      for (int nt = 0; nt < 4; ++nt)
#pragma unroll
        for (int r = 0; r < 4; ++r)
          zl[(kq * 16 + r4 + r) * 66 + (nt << 4) + fr] = acc[nt][r];
    }
    __syncthreads();
    if (kq >= 2) {
#pragma unroll
      for (int nt = 0; nt < 4; ++nt)
#pragma unroll
        for (int r = 0; r < 4; ++r)
          zl[((kq - 2) * 16 + r4 + r) * 66 + (nt << 4) + fr] += acc[nt][r];
    }
    __syncthreads();

    // 5) epilogue: validate Z now (overlapped with compute above), then gates
    int ztries = 0;
    for (;;) {
      u32 zbad = 0;
#pragma unroll
      for (int g = 0; g < 4; ++g) zbad |= ((u32)(zw[g] >> 48) ^ zexp);
      if (__ballot(zbad != 0) == 0ull) break;
      __builtin_amdgcn_s_sleep(1);
#pragma unroll
      for (int g = 0; g < 4; ++g) LD8C(zw[g], zb + ((size_t)g << 9));
      VM0();
      if (++ztries > 500000) { if (ln == 0) mark_err(err); break; }
    }
    float z4[4];
#pragma unroll
    for (int g = 0; g < 4; ++g)
      z4[g] = zl[row * 66 + (g << 4) + hc] + zl[(16 + row) * 66 + (g << 4) + hc]
            + zval(zw[g]) + bsv[g];
    float sf = sigm(z4[0]);
    float si = sigm(z4[1]);
    float tg = tanhf(z4[2]);
    float sog = sigm(z4[3]);
    float hn = sog * tanhf(creg);               // tanh of OLD c (faithful to reference)
    creg = creg * sf + tg * si;
    u64 word = pack3(hn, (u32)(t + 1));
    size_t ho = (size_t)((t + 1) & hrm) * 8192 + (size_t)row * 512 + (bid << 4) + hc;
    ST8C(hG + ho, word);
    if (LAYER == 2)
      h2hi[(size_t)(t + 1) * 16384 + (size_t)(p * 16 + row) * 512 + (bid << 4) + hc] =
          (u16)(word & 0xFFFFu);
    __syncthreads();
    if (tid == 0) ST4C(progSelf + bid, (u32)(t + 1));  // progress flag (backpressure)
  }
}

// ---------- Z0 worker: strip s (64 cols), parity q; Z0 = x @ W0x (6-step lead) ----------
__device__ void worker_z0(char* smem, int s, int q, const float* __restrict__ x,
                          const u16* __restrict__ W0T, u64* Z0R,
                          const u32* prog1, u32* err) {
  u16* wl0 = (u16*)smem;                        // [2 planes][64 rows][1024B] 128KB
  float* zl = (float*)(smem + 131072);          // [32][66]
  const int tid = threadIdx.x;

#pragma unroll 1
  for (int it = 0; it < 32; ++it) {             // stage W0x rows 64s..64s+63, k<512, planes 0,1
    int id = it * 256 + tid;
    int pl = id >> 12, rem = id & 4095, rho = rem >> 6, m = rem & 63;
    u32x4 v = *(const u32x4*)(W0T + (size_t)pl * WPS + (size_t)(64 * s + rho) * 1024 + m * 8);
    int dst = pl * 65536 + rho * 1024 + ((m << 4) ^ ((rho & 7) << 4));
    *(u32x4*)((char*)wl0 + dst) = v;
  }

  const int ln = tid & 63, kq = tid >> 6;
  const int fr = ln & 15, kg8 = (ln >> 4) << 3;
  const int row = tid >> 4, c4 = (tid & 15) * 4;
  const int ka = kq * 128 + kg8;
  u32 lastbp[2] = {0, 0};
  int bail = 0;
  __syncthreads();

#pragma unroll 1
  for (int k = 0;; ++k) {
    int t = 2 * k + q;
    if (t > 511) break;
    int nz = (k < 3) ? 2 : 1;
#pragma unroll 1
    for (int e = 0; e < nz; ++e) {
      int tz = (e == 0 && k < 3) ? t : t + 6;
      if (tz > 511) continue;
#pragma unroll 1
      for (int p = 0; p < 2; ++p) {
        if (kq == 0 && tz >= ZRS)
          wait_slots(prog1 + p * 32, ln, (u32)(tz - ZRS + 1), &lastbp[p], &bail, err);
        const float* xb = x + (size_t)(p * 16 + fr) * TT * 512 + (size_t)tz * 512 + ka;
        f32x4 acc[4] = {{0.f,0.f,0.f,0.f},{0.f,0.f,0.f,0.f},{0.f,0.f,0.f,0.f},{0.f,0.f,0.f,0.f}};
#pragma unroll
        for (int kt = 0; kt < 4; ++kt) {
          f32x4 f0 = *(const f32x4*)(xb + kt * 32);
          f32x4 f1 = *(const f32x4*)(xb + kt * 32 + 4);
          u32 r0[4], r1[4], r2[4];
#pragma unroll
          for (int j = 0; j < 4; ++j) {
            float v0 = (j < 2) ? f0[j * 2] : f1[(j - 2) * 2];
            float v1 = (j < 2) ? f0[j * 2 + 1] : f1[(j - 2) * 2 + 1];
            u32 pk0 = cvtpk(v0, v1);
            float h0 = __builtin_bit_cast(float, pk0 << 16);
            float h1f = __builtin_bit_cast(float, pk0 & 0xFFFF0000u);
            float q0 = v0 - h0, q1 = v1 - h1f;
            u32 pk1 = cvtpk(q0, q1);
            float g0 = __builtin_bit_cast(float, pk1 << 16);
            float g1 = __builtin_bit_cast(float, pk1 & 0xFFFF0000u);
            u32 s0 = __builtin_bit_cast(u32, q0 - g0);
            u32 s1 = __builtin_bit_cast(u32, q1 - g1);
            r0[j] = pk0; r1[j] = pk1;
            r2[j] = (s0 >> 16) | (s1 & 0xFFFF0000u);
          }
          bf16x8 a0 = __builtin_bit_cast(bf16x8, *(u32x4*)r0);
          bf16x8 a1 = __builtin_bit_cast(bf16x8, *(u32x4*)r1);
          bf16x8 a2 = __builtin_bit_cast(bf16x8, *(u32x4*)r2);
#pragma unroll
          for (int nt = 0; nt < 4; ++nt) {
            int rho = (nt << 4) + fr;
            int kb = ((ka + kt * 32) << 1) ^ ((rho & 7) << 4);
            bf16x8 w0 = *(const bf16x8*)((char*)wl0 + rho * 1024 + kb);
            bf16x8 w1 = *(const bf16x8*)((char*)wl0 + 65536 + rho * 1024 + kb);
            bf16x8 w2 = *(const bf16x8*)(W0T + 2 * WPS + (size_t)(64 * s + rho) * 1024 + ka + kt * 32);
            acc[nt] = mfma16(a0, w0, acc[nt]);
            acc[nt] = mfma16(a1, w0, acc[nt]);
            acc[nt] = mfma16(a2, w0, acc[nt]);
            acc[nt] = mfma16(a0, w1, acc[nt]);
            acc[nt] = mfma16(a1, w1, acc[nt]);
            acc[nt] = mfma16(a0, w2, acc[nt]);
          }
        }
        const int r4 = (ln >> 4) << 2;
        if (kq < 2) {
#pragma unroll
          for (int nt = 0; nt < 4; ++nt)
#pragma unroll
            for (int r = 0; r < 4; ++r)
              zl[(kq * 16 + r4 + r) * 66 + (nt << 4) + fr] = acc[nt][r];
        }
        __syncthreads();
        if (kq >= 2) {
#pragma unroll
          for (int nt = 0; nt < 4; ++nt)
#pragma unroll
            for (int r = 0; r < 4; ++r)
              zl[((kq - 2) * 16 + r4 + r) * 66 + (nt << 4) + fr] += acc[nt][r];
        }
        __syncthreads();
        u64 wv[4];
#pragma unroll
        for (int i = 0; i < 4; ++i) {
          float v = zl[row * 66 + c4 + i] + zl[(16 + row) * 66 + c4 + i];
          wv[i] = pack3(v, (u32)(tz + 1));
        }
        u64* dst = Z0R + (size_t)p * ZRS * 16 * 2048 + (size_t)(tz & (ZRS - 1)) * (16 * 2048)
                 + (size_t)row * 2048 + 64 * s + c4;
        u32x4 stA = { (u32)wv[0], (u32)(wv[0] >> 32), (u32)wv[1], (u32)(wv[1] >> 32) };
        u32x4 stB = { (u32)wv[2], (u32)(wv[2] >> 32), (u32)wv[3], (u32)(wv[3] >> 32) };
        ST16C(dst, stA);
        ST16C(dst + 2, stB);
        __syncthreads();
      }
    }
  }
}

// ---------- Zc worker: strip s (64 cols), parity q; Zc = h1(t+1) @ W1x ----------
__device__ void worker_zc(char* smem, int s, int q,
                          const u16* __restrict__ W1T, const u64* h1G, u64* ZcR,
                          const u32* prog2, u32* err) {
  u16* wl1 = (u16*)smem;                        // [2 planes][64 rows][1024B] 128KB
  float* zl = (float*)(smem + 131072);          // [32][66]
  const int tid = threadIdx.x;

#pragma unroll 1
  for (int it = 0; it < 32; ++it) {             // stage W1x rows 64s..64s+63, k<512, planes 0,1
    int id = it * 256 + tid;
    int pl = id >> 12, rem = id & 4095, rho = rem >> 6, m = rem & 63;
    u32x4 v = *(const u32x4*)(W1T + (size_t)pl * WPS + (size_t)(64 * s + rho) * 1024 + m * 8);
    int dst = pl * 65536 + rho * 1024 + ((m << 4) ^ ((rho & 7) << 4));
    *(u32x4*)((char*)wl1 + dst) = v;
  }

  const int ln = tid & 63, kq = tid >> 6;
  const int fr = ln & 15, kg8 = (ln >> 4) << 3;
  const int row = tid >> 4, c4 = (tid & 15) * 4;
  const int ka = kq * 128 + kg8;
  const int pcol = ((ln >> 1) << 4) + ((ln & 1) << 9);
  u32 last2[2] = {0, 0};
  int bail = 0;
  __syncthreads();

#pragma unroll 1
  for (int k = 0;; ++k) {
    int t = 2 * k + q;
    if (t > 511) break;
#pragma unroll 1
    for (int p = 0; p < 2; ++p) {
      if (kq == 0 && t >= ZRS)
        wait_slots(prog2 + p * 32, ln, (u32)(t - ZRS + 1), &last2[p], &bail, err);
      const size_t sb = (size_t)p * HRS * 8192 + (size_t)((t + 1) & (HRS - 1)) * 8192;
      const u64* hb = h1G + sb + (size_t)fr * 512 + ka;
      const u32 texp = (u32)(t + 1);
      head_poll(h1G + sb + pcol, texp, err);    // all-producer coverage
      u32x4 hv[4][4];
      int tries = 0;
      for (;;) {
#pragma unroll
        for (int kt = 0; kt < 4; ++kt)
#pragma unroll
          for (int j = 0; j < 4; ++j) LD16C(hv[kt][j], hb + kt * 32 + 2 * j);
        VM0();
        u32 bad = 0;
#pragma unroll
        for (int kt = 0; kt < 4; ++kt)
#pragma unroll
          for (int j = 0; j < 4; ++j)
            bad |= ((hv[kt][j].y >> 16) ^ texp) | ((hv[kt][j].w >> 16) ^ texp);
        if (__ballot(bad != 0) == 0ull) break;
        if (++tries > 500000) { if (ln == 0) mark_err(err); break; }
        __builtin_amdgcn_s_sleep(1);
      }
      f32x4 acc[4] = {{0.f,0.f,0.f,0.f},{0.f,0.f,0.f,0.f},{0.f,0.f,0.f,0.f},{0.f,0.f,0.f,0.f}};
#pragma unroll
      for (int kt = 0; kt < 4; ++kt) {
        u32 r0[4], r1[4], r2[4];
#pragma unroll
        for (int j = 0; j < 4; ++j) {
          u32 lo0 = hv[kt][j].x, hi0 = hv[kt][j].y, lo1 = hv[kt][j].z, hi1 = hv[kt][j].w;
          r0[j] = (lo0 & 0xFFFFu) | (lo1 << 16);
          r1[j] = (lo0 >> 16) | (lo1 & 0xFFFF0000u);
          r2[j] = (hi0 & 0xFFFFu) | (hi1 << 16);
        }
        bf16x8 a0 = __builtin_bit_cast(bf16x8, *(u32x4*)r0);
        bf16x8 a1 = __builtin_bit_cast(bf16x8, *(u32x4*)r1);
        bf16x8 a2 = __builtin_bit_cast(bf16x8, *(u32x4*)r2);
#pragma unroll
        for (int nt = 0; nt < 4; ++nt) {
          int rho = (nt << 4) + fr;
          int kb = ((ka + kt * 32) << 1) ^ ((rho & 7) << 4);
          bf16x8 w0 = *(const bf16x8*)((char*)wl1 + rho * 1024 + kb);
          bf16x8 w1 = *(const bf16x8*)((char*)wl1 + 65536 + rho * 1024 + kb);
          bf16x8 w2 = *(const bf16x8*)(W1T + 2 * WPS + (size_t)(64 * s + rho) * 1024 + ka + kt * 32);
          acc[nt] = mfma16(a0, w0, acc[nt]);
          acc[nt] = mfma16(a1, w0, acc[nt]);
          acc[nt] = mfma16(a2, w0, acc[nt]);
          acc[nt] = mfma16(a0, w1, acc[nt]);
          acc[nt] = mfma16(a1, w1, acc[nt]);
          acc[nt] = mfma16(a0, w2, acc[nt]);
        }
      }
      const int r4 = (ln >> 4) << 2;
      if (kq < 2) {
#pragma unroll
        for (int nt = 0; nt < 4; ++nt)
#pragma unroll
          for (int r = 0; r < 4; ++r)
            zl[(kq * 16 + r4 + r) * 66 + (nt << 4) + fr] = acc[nt][r];
      }
      __syncthreads();
      if (kq >= 2) {
#pragma unroll
        for (int nt = 0; nt < 4; ++nt)
#pragma unroll
          for (int r = 0; r < 4; ++r)
            zl[((kq - 2) * 16 + r4 + r) * 66 + (nt << 4) + fr] += acc[nt][r];
      }
      __syncthreads();
      u64 wv[4];
#pragma unroll
      for (int i = 0; i < 4; ++i) {
        float v = zl[row * 66 + c4 + i] + zl[(16 + row) * 66 + c4 + i];
        wv[i] = pack3(v, (u32)(t + 1));
      }
      u64* dst = ZcR + (size_t)p * ZRS * 16 * 2048 + (size_t)(t & (ZRS - 1)) * (16 * 2048)
               + (size_t)row * 2048 + 64 * s + c4;
      u32x4 stA = { (u32)wv[0], (u32)(wv[0] >> 32), (u32)wv[1], (u32)(wv[1] >> 32) };
      u32x4 stB = { (u32)wv[2], (u32)(wv[2] >> 32), (u32)wv[3], (u32)(wv[3] >> 32) };
      ST16C(dst, stA);
      ST16C(dst + 2, stB);
      __syncthreads();
    }
  }
}

// ---------- persistent kernel: 256 blocks, r8-role map ----------
// r8<2: L1 chains; r8<4: L2 chains; r8 in {4,5}: Zc workers; r8 in {6,7}: Z0 workers.
__global__ void __launch_bounds__(256, 1) mega(
    const float* __restrict__ x,
    const float* __restrict__ bias0, const float* __restrict__ bias1,
    const u16* __restrict__ W0T, const u16* __restrict__ W1T,
    u64* Z0R, u64* ZcR, u64* h1G, u64* h2G, u16* h2hi, u32* flags) {
  __shared__ char smem[139520];
  const int blk = blockIdx.x;
  const int r8 = blk & 7, g8 = blk >> 3;
  u32* prog1 = flags;          // [2][32]
  u32* prog2 = flags + 64;     // [2][32]
  u32* err = flags + 128;
  if (r8 < 2) {
    int p = r8;
    chain<1>(smem, p, g8, bias0, W0T,
             Z0R + (size_t)p * ZRS * 16 * 2048, h1G + (size_t)p * HRS * 8192,
             prog2 + p * 32, prog1 + p * 32, nullptr, err);
  } else if (r8 < 4) {
    int p = r8 - 2;
    chain<2>(smem, p, g8, bias1, W1T,
             ZcR + (size_t)p * ZRS * 16 * 2048, h2G + (size_t)p * HRS2 * 8192,
             nullptr, prog2 + p * 32, h2hi, err);
  } else if (r8 < 6) {
    worker_zc(smem, g8, r8 - 4, W1T, h1G, ZcR, prog2, err);
  } else {
    worker_z0(smem, g8, r8 - 6, x, W0T, Z0R, prog1, err);
  }
}

// ---------- projection from bf16-hi h2 history ----------
__global__ void proj(const u16* __restrict__ y,
                     const float* __restrict__ Wr, const float* __restrict__ br,
                     float* __restrict__ out) {
  int gw = (blockIdx.x * blockDim.x + threadIdx.x) >> 6;
  int ln = threadIdx.x & 63;
  int t = gw >> 5, b = gw & 31;
  const u16* yp = y + (size_t)(t + 1) * 16384 + (size_t)b * 512 + ln * 8;
  u32x4 v = *(const u32x4*)yp;
  float p0 = 0.f, p1 = 0.f;
#pragma unroll
  for (int jj = 0; jj < 8; ++jj) {
    u16 hh = (u16)((v[jj >> 1] >> ((jj & 1) * 16)) & 0xFFFFu);
    float yv = bf2f(hh);
    int j = ln * 8 + jj;
    p0 += yv * Wr[j * 2 + 0];
    p1 += yv * Wr[j * 2 + 1];
  }
#pragma unroll
  for (int o = 32; o; o >>= 1) { p0 += __shfl_down(p0, o, 64); p1 += __shfl_down(p1, o, 64); }
  if (ln == 0) {
    out[((size_t)b * 512 + t) * 2 + 0] = p0 + br[0];
    out[((size_t)b * 512 + t) * 2 + 1] = p1 + br[1];
  }
}

// ---------- diagnostics ----------
__global__ void fail_mark(float* out, float code) {
  if (threadIdx.x == 0 && blockIdx.x == 0) out[0] = code;
}
__global__ void err_check(const u32* flags, float* out) {
  if (threadIdx.x == 0 && blockIdx.x == 0) {
    u32 e = flags[128];
    if (e) out[0] = 1.0e6f + (float)e;
  }
}

// ---------- host ----------
extern "C" void kernel_launch(void* const* d_in, const int* in_sizes, int n_in,
                              void* d_out, int out_size, void* d_ws, size_t ws_size,
                              hipStream_t stream) {
  (void)in_sizes; (void)n_in; (void)out_size;
  const float* x  = (const float*)d_in[0];
  const float* W0 = (const float*)d_in[1];
  const float* b0 = (const float*)d_in[2];
  const float* W1 = (const float*)d_in[3];
  const float* b1 = (const float*)d_in[4];
  const float* Wr = (const float*)d_in[5];
  const float* br = (const float*)d_in[6];
  float* out = (float*)d_out;

  char* ws = (char*)d_ws;
  size_t off = 0;
  auto take = [&](size_t n) { char* p = ws + off; off = (off + n + 255) & ~(size_t)255; return p; };

  u16* W0T  = (u16*)take(3 * WPS * 2);                      // 12.6 MB
  u16* W1T  = (u16*)take(3 * WPS * 2);                      // 12.6 MB
  u64* Z0R  = (u64*)take((size_t)2 * ZRS * 16 * 2048 * 8);  // 4.2 MB
  u64* ZcR  = (u64*)take((size_t)2 * ZRS * 16 * 2048 * 8);  // 4.2 MB
  u64* h1G  = (u64*)take((size_t)2 * HRS * 8192 * 8);       // 2.1 MB
  u64* h2G  = (u64*)take((size_t)2 * HRS2 * 8192 * 8);      // 0.52 MB
  u16* h2hi = (u16*)take((size_t)513 * 16384 * 2);          // 16.8 MB
  u32* flags = (u32*)take(129 * 4);                         // total ~53 MB

  if (off > ws_size) {                   // visible failure: absmax ~= 2e6
    fail_mark<<<1, 1, 0, stream>>>(out, 2.0e6f);
    return;
  }

  (void)hipMemsetAsync(flags, 0, 129 * 4, stream);
  // zero ALL rings (h(0)=0 with tag 0; no garbage can alias a future tag); replay-safe
  (void)hipMemsetAsync(Z0R, 0, (size_t)2 * ZRS * 16 * 2048 * 8, stream);
  (void)hipMemsetAsync(ZcR, 0, (size_t)2 * ZRS * 16 * 2048 * 8, stream);
  (void)hipMemsetAsync(h1G, 0, (size_t)2 * HRS * 8192 * 8, stream);
  (void)hipMemsetAsync(h2G, 0, (size_t)2 * HRS2 * 8192 * 8, stream);

  prep_w<<<8192, 256, 0, stream>>>(W0, W0T);
  prep_w<<<8192, 256, 0, stream>>>(W1, W1T);
  (void)hipGetLastError();
  mega<<<256, 256, 0, stream>>>(x, b0, b1, W0T, W1T,
                                Z0R, ZcR, h1G, h2G, h2hi, flags);
  if (hipGetLastError() != hipSuccess) {  // visible failure: absmax ~= 3e6
    fail_mark<<<1, 1, 0, stream>>>(out, 3.0e6f);
    return;
  }
  proj<<<4096, 256, 0, stream>>>(h2hi, Wr, br, out);
  err_check<<<1, 1, 0, stream>>>(flags, out);   // absmax ~= 1e6+n on timeout
}